// Round 1
// baseline (219.732 us; speedup 1.0000x reference)
//
#include <hip/hip_runtime.h>

// Conv2d 3x3 s1 p1 as implicit GEMM, bf16 MFMA, fp32 accumulate.
// N=32, Cin=128, H=W=56, Cout=256. M=100352, K=1152 (kh,kw outer / ci inner).
// R3: padded-NHWC xt (58x58, zero border) -> no halo logic in GEMM.
//     GEMM: 256x256 tile, 8 waves (per-wave 128m x 64co), BK=64,
//     A triple-buffer + B double-buffer (160 KB LDS), 4 phases/K-tile,
//     counted vmcnt(4), setprio around MFMA clusters, XOR piece-swizzle.

#define NB   32
#define CIN  128
#define HH   56
#define WWD  56
#define COUT 256
#define HWP  3136      // 56*56
#define KTOT 1152      // 9*128
#define HP   58        // padded spatial dim
#define XTN  (HP*HP*CIN)   // 430592 elems per image

typedef __bf16 bf16x8 __attribute__((ext_vector_type(8)));
typedef float  f32x4  __attribute__((ext_vector_type(4)));
typedef unsigned short u16;
typedef u16 u16x4 __attribute__((ext_vector_type(4)));
typedef u16 u16x8 __attribute__((ext_vector_type(8)));

__device__ __forceinline__ u16 f2b(float f) {
  unsigned u = __float_as_uint(f);
  u += 0x7fffu + ((u >> 16) & 1u);
  return (u16)(u >> 16);
}

__device__ __forceinline__ void load_lds16(const u16* g, u16* l) {
  __builtin_amdgcn_global_load_lds(
      (const __attribute__((address_space(1))) unsigned int*)g,
      (__attribute__((address_space(3))) unsigned int*)l, 16, 0, 0);
}

// x: [32][128][3136] f32 -> xt: [32][58][58][128] bf16 (NCHW -> padded NHWC + cvt)
// Interior only; border zeroed by k_transform_w.
__global__ __launch_bounds__(256) void k_transpose_x(const float* __restrict__ x,
                                                     u16* __restrict__ xt) {
  __shared__ u16 tile[64][68];   // row = c; 136B row stride
  const int n  = blockIdx.z;
  const int p0 = blockIdx.x * 64;
  const int c0 = blockIdx.y * 64;
  const int t  = threadIdx.x;

  const float* xp = x + (size_t)n * CIN * HWP + (size_t)c0 * HWP + p0;
  const int pl = (t & 15) * 4;   // pixel offset within tile
  const int cr = t >> 4;         // channel row 0..15 (+16j)
#pragma unroll
  for (int j = 0; j < 4; ++j) {
    int c = cr + j * 16;
    f32x4 v = *(const f32x4*)&xp[(size_t)c * HWP + pl];
    u16x4 h;
    h[0] = f2b(v[0]); h[1] = f2b(v[1]); h[2] = f2b(v[2]); h[3] = f2b(v[3]);
    *(u16x4*)&tile[c][pl] = h;
  }
  __syncthreads();
  u16* xb = xt + (size_t)n * XTN + c0;
  const int ch = (t & 7) * 8;    // channel chunk
  const int pr = t >> 3;         // pixel row 0..31 (+32j)
#pragma unroll
  for (int j = 0; j < 2; ++j) {
    int p  = pr + j * 32;
    int s  = p0 + p;
    int oh = s / WWD;
    int ow = s - oh * WWD;
    u16x8 o;
#pragma unroll
    for (int i = 0; i < 8; ++i) o[i] = tile[ch + i][p];
    *(u16x8*)&xb[((size_t)(oh + 1) * HP + (ow + 1)) * CIN + ch] = o;
  }
}

// w: [256][128][3][3] f32 -> Wt: [256][1152] bf16 with k = (kh*3+kw)*128 + ci
// Also zeroes the xt border (32 * 228 pixels * 128 ch = 933888 elems).
__global__ __launch_bounds__(256) void k_transform_w(const float* __restrict__ w,
                                                     u16* __restrict__ Wt,
                                                     u16* __restrict__ xt) {
  int o = blockIdx.x * 256 + threadIdx.x;
  if (o < COUT * KTOT) {
    int co  = o / KTOT;
    int rem = o - co * KTOT;
    int kk  = rem >> 7;      // (kh*3+kw)
    int ci  = rem & 127;
    int kh  = kk / 3;
    int kw  = kk - kh * 3;
    Wt[o] = f2b(w[(((size_t)co * CIN + ci) * 3 + kh) * 3 + kw]);
  }
#pragma unroll
  for (int j = 0; j < 4; ++j) {
    unsigned e = (unsigned)o + j * 294912u;
    if (e < 933888u) {
      unsigned n  = e / 29184u;         // 228*128
      unsigned rm = e - n * 29184u;
      unsigned bp = rm >> 7;            // border pixel 0..227
      unsigned ch = rm & 127u;
      unsigned ih, iw;
      if (bp < 58u)       { ih = 0;  iw = bp; }
      else if (bp < 116u) { ih = 57; iw = bp - 58u; }
      else { unsigned c2 = bp - 116u; ih = 1u + (c2 >> 1); iw = (c2 & 1u) ? 57u : 0u; }
      xt[(((size_t)n * HP + ih) * HP + iw) * CIN + ch] = (u16)0;
    }
  }
}

// ---- GEMM: grid (392), block 512 (8 waves, 2m x 4co), per-wave 128m x 64co.
// LDS (160 KB, elems): A bufs {0,16384,32768} (32KB each, kt%3),
//                      B bufs {49152,65536}   (32KB each, kt%2).
// Per K-tile kt: read A(kt),B(kt); issue B(kt+1) [P0,P1], A(kt+2) [P2,P3];
// vmcnt(4) at P3 confirms {A(kt+1),B(kt+1)}, leaves A(kt+2) in flight.

#define RD_A(qm_) do { _Pragma("unroll") for (int kk = 0; kk < 2; ++kk) \
    { _Pragma("unroll") for (int ti = 0; ti < 4; ++ti) \
      a[kk][ti] = *(const bf16x8*)&lds[eA + (wm*128 + (qm_)*64 + ti*16 + r)*64 \
                                        + (((kk*4 + q) ^ r7))*8]; } } while (0)

#define RD_B(qn_) do { _Pragma("unroll") for (int kk = 0; kk < 2; ++kk) \
    { _Pragma("unroll") for (int tj = 0; tj < 2; ++tj) \
      b[kk][tj] = *(const bf16x8*)&lds[eB + (wn*64 + (qn_)*32 + tj*16 + r)*64 \
                                        + (((kk*4 + q) ^ r7))*8]; } } while (0)

#define MM(qm_, qn_) do { _Pragma("unroll") for (int kk = 0; kk < 2; ++kk) \
    { _Pragma("unroll") for (int ti = 0; ti < 4; ++ti) \
      { _Pragma("unroll") for (int tj = 0; tj < 2; ++tj) \
        acc[(qm_)*4 + ti][(qn_)*2 + tj] = __builtin_amdgcn_mfma_f32_16x16x32_bf16( \
            a[kk][ti], b[kk][tj], acc[(qm_)*4 + ti][(qn_)*2 + tj], 0, 0, 0); } } } while (0)

__global__ __launch_bounds__(512, 2) void k_conv_gemm(
    const u16* __restrict__ xt, const u16* __restrict__ Wt,
    const float* __restrict__ bias, float* __restrict__ out) {
  extern __shared__ u16 lds[];
  const int tid  = threadIdx.x;
  const int wave = tid >> 6;
  const int lane = tid & 63;
  const int m0   = blockIdx.x * 256;

  const int wm = wave >> 2;   // 0..1 : m-half of block
  const int wn = wave & 3;    // 0..3 : co-quarter of block
  const int r  = lane & 15;
  const int q  = lane >> 4;
  const int r7 = r & 7;

  // staging lane map: 8 rows x 8 swizzled 16B pieces per instruction
  const int rsub = lane >> 3;
  const int ps8  = ((lane & 7) ^ rsub) * 8;   // swizzled global k-offset (elems)

  int pbA[4], pbB[4], ldo[4];
#pragma unroll
  for (int j = 0; j < 4; ++j) {
    const int rowb = wave * 8 + j * 64;
    const int m  = m0 + rowb + rsub;
    const int n  = m / HWP;
    const int s  = m - n * HWP;
    const int oh = s / WWD;
    const int ow = s - oh * WWD;
    pbA[j] = ((n * HP + oh) * HP + ow) * CIN + ps8;   // + (kh*58+kw)*128 + ci0 at issue
    pbB[j] = (rowb + rsub) * KTOT + ps8;              // + kt*64 at issue
    ldo[j] = rowb * 64;                               // LDS elem offset of row block
  }
  float bias_r[4];
#pragma unroll
  for (int tj = 0; tj < 4; ++tj) bias_r[tj] = bias[wn * 64 + tj * 16 + r];

  f32x4 acc[8][4];
#pragma unroll
  for (int i = 0; i < 8; ++i)
#pragma unroll
    for (int jj = 0; jj < 4; ++jj) acc[i][jj] = (f32x4){0.f, 0.f, 0.f, 0.f};

  // Prologue: stage B(0) -> bufB0, A(0) -> bufA0, A(1) -> bufA1 (FIFO: B0,A0,A1)
#pragma unroll
  for (int j = 0; j < 4; ++j) load_lds16(Wt + pbB[j], &lds[49152 + ldo[j]]);
#pragma unroll
  for (int j = 0; j < 4; ++j) load_lds16(xt + pbA[j], &lds[0 + ldo[j]]);       // kt0: kh=kw=0,ci0=0
#pragma unroll
  for (int j = 0; j < 4; ++j) load_lds16(xt + pbA[j] + 64, &lds[16384 + ldo[j]]); // kt1: ci0=64
  asm volatile("s_waitcnt vmcnt(4)" ::: "memory");   // B(0),A(0) landed; A(1) in flight
  __builtin_amdgcn_s_barrier();

  bf16x8 a[2][4], b[2][2];
  int bA = 0, bB = 0;

#pragma unroll 1
  for (int kt = 0; kt < 18; ++kt) {
    const int eA  = bA * 16384;
    const int eB  = 49152 + bB * 16384;
    const int sAo = (bA == 0) ? 32768 : (bA - 1) * 16384;   // (kt+2)%3 buf
    const int sBo = 49152 + ((bB ^ 1) * 16384);             // (kt+1)%2 buf
    const int koffB = (kt + 1) * 64;
    const int kt2  = kt + 2;
    const int ksp2 = kt2 >> 1;
    const int kh2  = (ksp2 >= 6) ? 2 : ((ksp2 >= 3) ? 1 : 0);
    const int kw2  = ksp2 - kh2 * 3;
    const int UA   = (kh2 * HP + kw2) * CIN + ((kt2 & 1) << 6);
    const bool doB = (kt < 17);
    const bool doA = (kt < 16);

    // ---- P0: quadrant (qm=0, qn=0); issue B(kt+1) half 1
    RD_A(0); RD_B(0);
    if (doB) { load_lds16(Wt + pbB[0] + koffB, &lds[sBo + ldo[0]]);
               load_lds16(Wt + pbB[1] + koffB, &lds[sBo + ldo[1]]); }
    __builtin_amdgcn_s_barrier();
    __builtin_amdgcn_s_setprio(1);
    MM(0, 0);
    __builtin_amdgcn_s_setprio(0);
    __builtin_amdgcn_s_barrier();

    // ---- P1: (qm=0, qn=1); issue B(kt+1) half 2
    RD_B(1);
    if (doB) { load_lds16(Wt + pbB[2] + koffB, &lds[sBo + ldo[2]]);
               load_lds16(Wt + pbB[3] + koffB, &lds[sBo + ldo[3]]); }
    __builtin_amdgcn_s_barrier();
    __builtin_amdgcn_s_setprio(1);
    MM(0, 1);
    __builtin_amdgcn_s_setprio(0);
    __builtin_amdgcn_s_barrier();

    // ---- P2: (qm=1, qn=1); issue A(kt+2) half 1
    RD_A(1);
    if (doA) { load_lds16(xt + pbA[0] + UA, &lds[sAo + ldo[0]]);
               load_lds16(xt + pbA[1] + UA, &lds[sAo + ldo[1]]); }
    __builtin_amdgcn_s_barrier();
    __builtin_amdgcn_s_setprio(1);
    MM(1, 1);
    __builtin_amdgcn_s_setprio(0);
    __builtin_amdgcn_s_barrier();

    // ---- P3: (qm=1, qn=0); issue A(kt+2) half 2; counted vmcnt
    RD_B(0);
    if (doA) { load_lds16(xt + pbA[2] + UA, &lds[sAo + ldo[2]]);
               load_lds16(xt + pbA[3] + UA, &lds[sAo + ldo[3]]); }
    if (kt < 16) { asm volatile("s_waitcnt vmcnt(4)" ::: "memory"); }
    else         { asm volatile("s_waitcnt vmcnt(0)" ::: "memory"); }
    __builtin_amdgcn_s_barrier();
    __builtin_amdgcn_s_setprio(1);
    MM(1, 0);
    __builtin_amdgcn_s_setprio(0);
    __builtin_amdgcn_s_barrier();

    bA = (bA == 2) ? 0 : bA + 1;
    bB ^= 1;
  }

  // Epilogue: C/D layout col=lane&15 (co), row=q*4+e (m). f32x4 stores.
#pragma unroll
  for (int ti = 0; ti < 8; ++ti) {
    const int m4 = m0 + wm * 128 + ti * 16 + q * 4;   // 4-aligned, never crosses n
    const int n  = m4 / HWP;
    const int s  = m4 - n * HWP;
    float* op = out + (size_t)n * COUT * HWP + s;
#pragma unroll
    for (int tj = 0; tj < 4; ++tj) {
      const int co = wn * 64 + tj * 16 + r;
      f32x4 v = acc[ti][tj];
      const float bv = bias_r[tj];
      v[0] += bv; v[1] += bv; v[2] += bv; v[3] += bv;
      *(f32x4*)(op + (size_t)co * HWP) = v;
    }
  }
}

extern "C" void kernel_launch(void* const* d_in, const int* in_sizes, int n_in,
                              void* d_out, int out_size, void* d_ws, size_t ws_size,
                              hipStream_t stream) {
  const float* x    = (const float*)d_in[0];
  const float* w    = (const float*)d_in[1];
  const float* bias = (const float*)d_in[2];
  float* out        = (float*)d_out;

  u16* xt = (u16*)d_ws;                       // 13,778,944 bf16 = 27.6 MB (padded NHWC)
  u16* Wt = xt + (size_t)NB * XTN;            // 294,912 bf16

  static bool attr_done = false;
  if (!attr_done) {
    hipFuncSetAttribute(reinterpret_cast<const void*>(k_conv_gemm),
                        hipFuncAttributeMaxDynamicSharedMemorySize, 163840);
    attr_done = true;
  }

  k_transform_w<<<dim3(1152), dim3(256), 0, stream>>>(w, Wt, xt);
  k_transpose_x<<<dim3(49, 2, 32), dim3(256), 0, stream>>>(x, xt);
  k_conv_gemm<<<dim3(392), dim3(512), 163840, stream>>>(xt, Wt, bias, out);
}

// Round 2
// 218.837 us; speedup vs baseline: 1.0041x; 1.0041x over previous
//
#include <hip/hip_runtime.h>

// Conv2d 3x3 s1 p1 as implicit GEMM, bf16 MFMA, fp32 accumulate.
// N=32, Cin=128, H=W=56, Cout=256. M=100352, K=1152 (kh,kw outer / ci inner).
// R4: padded-NHWC xt (58x58, zero border) + R2's proven 128x128/4-wave geometry
//     (1568 blocks, ~2 blocks/CU -> store overlap, no lockstep tail) +
//     minimal 2-phase counted-vmcnt double-buffer (64 KB LDS, 1 barrier/K-tile) +
//     operand swap for f32x4 epilogue stores + bijective XCD chunk swizzle.

#define NB   32
#define CIN  128
#define HH   56
#define WWD  56
#define COUT 256
#define HWP  3136      // 56*56
#define KTOT 1152      // 9*128
#define HP   58        // padded spatial dim
#define XTN  (HP*HP*CIN)   // 430592 elems per image

typedef __bf16 bf16x8 __attribute__((ext_vector_type(8)));
typedef float  f32x4  __attribute__((ext_vector_type(4)));
typedef unsigned short u16;
typedef u16 u16x4 __attribute__((ext_vector_type(4)));
typedef u16 u16x8 __attribute__((ext_vector_type(8)));

__device__ __forceinline__ u16 f2b(float f) {
  unsigned u = __float_as_uint(f);
  u += 0x7fffu + ((u >> 16) & 1u);
  return (u16)(u >> 16);
}

__device__ __forceinline__ void load_lds16(const u16* g, u16* l) {
  __builtin_amdgcn_global_load_lds(
      (const __attribute__((address_space(1))) unsigned int*)g,
      (__attribute__((address_space(3))) unsigned int*)l, 16, 0, 0);
}

// x: [32][128][3136] f32 -> xt: [32][58][58][128] bf16 (NCHW -> padded NHWC + cvt)
// Interior only; border zeroed by k_transform_w.
__global__ __launch_bounds__(256) void k_transpose_x(const float* __restrict__ x,
                                                     u16* __restrict__ xt) {
  __shared__ u16 tile[64][68];   // row = c; 136B row stride
  const int n  = blockIdx.z;
  const int p0 = blockIdx.x * 64;
  const int c0 = blockIdx.y * 64;
  const int t  = threadIdx.x;

  const float* xp = x + (size_t)n * CIN * HWP + (size_t)c0 * HWP + p0;
  const int pl = (t & 15) * 4;   // pixel offset within tile
  const int cr = t >> 4;         // channel row 0..15 (+16j)
#pragma unroll
  for (int j = 0; j < 4; ++j) {
    int c = cr + j * 16;
    f32x4 v = *(const f32x4*)&xp[(size_t)c * HWP + pl];
    u16x4 h;
    h[0] = f2b(v[0]); h[1] = f2b(v[1]); h[2] = f2b(v[2]); h[3] = f2b(v[3]);
    *(u16x4*)&tile[c][pl] = h;
  }
  __syncthreads();
  u16* xb = xt + (size_t)n * XTN + c0;
  const int ch = (t & 7) * 8;    // channel chunk
  const int pr = t >> 3;         // pixel row 0..31 (+32j)
#pragma unroll
  for (int j = 0; j < 2; ++j) {
    int p  = pr + j * 32;
    int s  = p0 + p;
    int oh = s / WWD;
    int ow = s - oh * WWD;
    u16x8 o;
#pragma unroll
    for (int i = 0; i < 8; ++i) o[i] = tile[ch + i][p];
    *(u16x8*)&xb[((size_t)(oh + 1) * HP + (ow + 1)) * CIN + ch] = o;
  }
}

// w: [256][128][3][3] f32 -> Wt: [256][1152] bf16 with k = (kh*3+kw)*128 + ci
// Also zeroes the xt border (32 * 228 pixels * 128 ch = 933888 elems).
__global__ __launch_bounds__(256) void k_transform_w(const float* __restrict__ w,
                                                     u16* __restrict__ Wt,
                                                     u16* __restrict__ xt) {
  int o = blockIdx.x * 256 + threadIdx.x;
  if (o < COUT * KTOT) {
    int co  = o / KTOT;
    int rem = o - co * KTOT;
    int kk  = rem >> 7;      // (kh*3+kw)
    int ci  = rem & 127;
    int kh  = kk / 3;
    int kw  = kk - kh * 3;
    Wt[o] = f2b(w[(((size_t)co * CIN + ci) * 3 + kh) * 3 + kw]);
  }
#pragma unroll
  for (int j = 0; j < 4; ++j) {
    unsigned e = (unsigned)o + j * 294912u;
    if (e < 933888u) {
      unsigned n  = e / 29184u;         // 228*128
      unsigned rm = e - n * 29184u;
      unsigned bp = rm >> 7;            // border pixel 0..227
      unsigned ch = rm & 127u;
      unsigned ih, iw;
      if (bp < 58u)       { ih = 0;  iw = bp; }
      else if (bp < 116u) { ih = 57; iw = bp - 58u; }
      else { unsigned c2 = bp - 116u; ih = 1u + (c2 >> 1); iw = (c2 & 1u) ? 57u : 0u; }
      xt[(((size_t)n * HP + ih) * HP + iw) * CIN + ch] = (u16)0;
    }
  }
}

// ---- GEMM: grid 1568 (784 m-tiles x 2 co-tiles), block 256 (4 waves).
// 128x128 tile, BK=64, 18 K-tiles. Double-buffered 64 KB LDS -> 2 blocks/CU.
// Per K-tile: STAGE(kt+1 -> buf^1) issued first, then ds_read+MFMA(buf),
// then vmcnt(0) (covers only the 8 stage loads, issued ~620cyc earlier) + 1 barrier.

__device__ __forceinline__ int uX_off(int kt) {
  int ksp = kt >> 1;
  int kh  = (ksp >= 6) ? 2 : ((ksp >= 3) ? 1 : 0);
  int kw  = ksp - kh * 3;
  return (kh * HP + kw) * CIN + ((kt & 1) << 6);
}

#define STG(buf_, uxo_, uwo_) do { _Pragma("unroll") \
  for (int c = 0; c < 4; ++c) { \
    load_lds16(Wt + pbW[c] + (uwo_), &lW[buf_][ldo[c]]); \
    load_lds16(xt + pbX[c] + (uxo_), &lX[buf_][ldo[c]]); } } while (0)

#define CMP(buf_) do { _Pragma("unroll") for (int kk = 0; kk < 2; ++kk) { \
    bf16x8 a[4], b[4]; const int sw = ((kk * 4 + q) ^ r7) * 8; \
    _Pragma("unroll") for (int ti = 0; ti < 4; ++ti) \
      a[ti] = *(const bf16x8*)&lX[buf_][(wm + ti * 16 + r) * 64 + sw]; \
    _Pragma("unroll") for (int tj = 0; tj < 4; ++tj) \
      b[tj] = *(const bf16x8*)&lW[buf_][(wc + tj * 16 + r) * 64 + sw]; \
    _Pragma("unroll") for (int ti = 0; ti < 4; ++ti) \
      _Pragma("unroll") for (int tj = 0; tj < 4; ++tj) \
        acc[ti][tj] = __builtin_amdgcn_mfma_f32_16x16x32_bf16( \
            a[ti], b[tj], acc[ti][tj], 0, 0, 0); } } while (0)

__global__ __launch_bounds__(256, 2) void k_conv_gemm(
    const u16* __restrict__ xt, const u16* __restrict__ Wt,
    const float* __restrict__ bias, float* __restrict__ out) {
  __shared__ u16 lW[2][8192];   // [buf][128 rows x 64 k], piece-swizzled
  __shared__ u16 lX[2][8192];

  const int tid  = threadIdx.x;
  const int wave = tid >> 6;
  const int lane = tid & 63;

  // bijective XCD chunk swizzle: 1568 = 8 * 196 exact
  const int bid  = blockIdx.x;
  const int orig = (bid & 7) * 196 + (bid >> 3);
  const int by   = orig / 784;
  const int bx   = orig - by * 784;
  const int m0   = bx * 128;
  const int co0  = by * 128;

  const int r  = lane & 15;
  const int q  = lane >> 4;
  const int r7 = r & 7;
  const int wm = (wave & 1) * 64;    // m offset of this wave's 64x64
  const int wc = (wave >> 1) * 64;   // co offset

  // staging lane map: 8 rows x 8 swizzled 16B pieces per instruction
  const int rsub = lane >> 3;
  const int pso  = ((lane & 7) ^ rsub) * 8;

  int pbX[4], pbW[4], ldo[4];
#pragma unroll
  for (int c = 0; c < 4; ++c) {
    const int rowb = wave * 32 + c * 8;
    const int m  = m0 + rowb + rsub;
    const int n  = m / HWP;
    const int s  = m - n * HWP;
    const int oh = s / WWD;
    const int ow = s - oh * WWD;
    pbX[c] = ((n * HP + oh) * HP + ow) * CIN + pso;
    pbW[c] = (co0 + rowb + rsub) * KTOT + pso;
    ldo[c] = rowb * 64;
  }
  float bias_r[4];
#pragma unroll
  for (int tj = 0; tj < 4; ++tj) bias_r[tj] = bias[co0 + wc + tj * 16 + r];

  f32x4 acc[4][4];
#pragma unroll
  for (int i = 0; i < 4; ++i)
#pragma unroll
    for (int j = 0; j < 4; ++j) acc[i][j] = (f32x4){0.f, 0.f, 0.f, 0.f};

  // Prologue: stage tile 0 -> buf0
  STG(0, 0, 0);
  asm volatile("s_waitcnt vmcnt(0)" ::: "memory");
  __builtin_amdgcn_s_barrier();

#pragma unroll 1
  for (int p = 0; p < 8; ++p) {
    const int kt = p * 2;
    STG(1, uX_off(kt + 1), (kt + 1) * 64);
    CMP(0);
    asm volatile("s_waitcnt vmcnt(0)" ::: "memory");
    __builtin_amdgcn_s_barrier();
    STG(0, uX_off(kt + 2), (kt + 2) * 64);
    CMP(1);
    asm volatile("s_waitcnt vmcnt(0)" ::: "memory");
    __builtin_amdgcn_s_barrier();
  }
  // kt=16 (buf0), kt=17 (buf1)
  STG(1, uX_off(17), 17 * 64);
  CMP(0);
  asm volatile("s_waitcnt vmcnt(0)" ::: "memory");
  __builtin_amdgcn_s_barrier();
  CMP(1);

  // Epilogue: mfma(a=X, b=W) -> col(lane&15)=co, row(q*4+e)=m.
  // f32x4 store along s (m4 is 4-aligned, never crosses a 3136-row).
#pragma unroll
  for (int ti = 0; ti < 4; ++ti) {
    const int m4 = m0 + wm + ti * 16 + q * 4;
    const int n  = m4 / HWP;
    const int s  = m4 - n * HWP;
    float* op = out + (size_t)n * COUT * HWP + s;
#pragma unroll
    for (int tj = 0; tj < 4; ++tj) {
      const int co = co0 + wc + tj * 16 + r;
      f32x4 v = acc[ti][tj];
      const float bv = bias_r[tj];
      v[0] += bv; v[1] += bv; v[2] += bv; v[3] += bv;
      *(f32x4*)(op + (size_t)co * HWP) = v;
    }
  }
}

extern "C" void kernel_launch(void* const* d_in, const int* in_sizes, int n_in,
                              void* d_out, int out_size, void* d_ws, size_t ws_size,
                              hipStream_t stream) {
  const float* x    = (const float*)d_in[0];
  const float* w    = (const float*)d_in[1];
  const float* bias = (const float*)d_in[2];
  float* out        = (float*)d_out;

  u16* xt = (u16*)d_ws;                       // 13,778,944 bf16 = 27.6 MB (padded NHWC)
  u16* Wt = xt + (size_t)NB * XTN;            // 294,912 bf16

  k_transform_w<<<dim3(1152), dim3(256), 0, stream>>>(w, Wt, xt);
  k_transpose_x<<<dim3(49, 2, 32), dim3(256), 0, stream>>>(x, xt);
  k_conv_gemm<<<dim3(1568), dim3(256), 0, stream>>>(xt, Wt, bias, out);
}

// Round 3
// 207.039 us; speedup vs baseline: 1.0613x; 1.0570x over previous
//
#include <hip/hip_runtime.h>

// Conv2d 3x3 s1 p1 as implicit GEMM, bf16 MFMA, fp32 accumulate.
// N=32, Cin=128, H=W=56, Cout=256. M=100352, K=1152 (kh,kw outer / ci inner).
// R5: m97-faithful GEMM (128x128 tile, 4 waves, SINGLE 32 KB LDS buffer,
//     2 syncthreads/K-tile -> 4 blocks/CU inter-block overlap) +
//     padded-NHWC xt (no halo logic) + f32x4 epilogue +
//     pair-preserving XCD chunk swizzle + launch_bounds(256,4) (VGPR=64).

#define NB   32
#define CIN  128
#define HH   56
#define WWD  56
#define COUT 256
#define HWP  3136      // 56*56
#define KTOT 1152      // 9*128
#define HP   58        // padded spatial dim
#define XTN  (HP*HP*CIN)   // 430592 elems per image

typedef __bf16 bf16x8 __attribute__((ext_vector_type(8)));
typedef float  f32x4  __attribute__((ext_vector_type(4)));
typedef unsigned short u16;
typedef u16 u16x4 __attribute__((ext_vector_type(4)));
typedef u16 u16x8 __attribute__((ext_vector_type(8)));

__device__ __forceinline__ u16 f2b(float f) {
  unsigned u = __float_as_uint(f);
  u += 0x7fffu + ((u >> 16) & 1u);
  return (u16)(u >> 16);
}

__device__ __forceinline__ void load_lds16(const u16* g, u16* l) {
  __builtin_amdgcn_global_load_lds(
      (const __attribute__((address_space(1))) unsigned int*)g,
      (__attribute__((address_space(3))) unsigned int*)l, 16, 0, 0);
}

// x: [32][128][3136] f32 -> xt: [32][58][58][128] bf16 (NCHW -> padded NHWC + cvt)
// Interior only; border zeroed by k_transform_w.
__global__ __launch_bounds__(256) void k_transpose_x(const float* __restrict__ x,
                                                     u16* __restrict__ xt) {
  __shared__ u16 tile[64][68];   // row = c; 136B row stride
  const int n  = blockIdx.z;
  const int p0 = blockIdx.x * 64;
  const int c0 = blockIdx.y * 64;
  const int t  = threadIdx.x;

  const float* xp = x + (size_t)n * CIN * HWP + (size_t)c0 * HWP + p0;
  const int pl = (t & 15) * 4;   // pixel offset within tile
  const int cr = t >> 4;         // channel row 0..15 (+16j)
#pragma unroll
  for (int j = 0; j < 4; ++j) {
    int c = cr + j * 16;
    f32x4 v = *(const f32x4*)&xp[(size_t)c * HWP + pl];
    u16x4 h;
    h[0] = f2b(v[0]); h[1] = f2b(v[1]); h[2] = f2b(v[2]); h[3] = f2b(v[3]);
    *(u16x4*)&tile[c][pl] = h;
  }
  __syncthreads();
  u16* xb = xt + (size_t)n * XTN + c0;
  const int ch = (t & 7) * 8;    // channel chunk
  const int pr = t >> 3;         // pixel row 0..31 (+32j)
#pragma unroll
  for (int j = 0; j < 2; ++j) {
    int p  = pr + j * 32;
    int s  = p0 + p;
    int oh = s / WWD;
    int ow = s - oh * WWD;
    u16x8 o;
#pragma unroll
    for (int i = 0; i < 8; ++i) o[i] = tile[ch + i][p];
    *(u16x8*)&xb[((size_t)(oh + 1) * HP + (ow + 1)) * CIN + ch] = o;
  }
}

// w: [256][128][3][3] f32 -> Wt: [256][1152] bf16 with k = (kh*3+kw)*128 + ci
// Also zeroes the xt border (32 * 228 pixels * 128 ch = 933888 elems).
__global__ __launch_bounds__(256) void k_transform_w(const float* __restrict__ w,
                                                     u16* __restrict__ Wt,
                                                     u16* __restrict__ xt) {
  int o = blockIdx.x * 256 + threadIdx.x;
  if (o < COUT * KTOT) {
    int co  = o / KTOT;
    int rem = o - co * KTOT;
    int kk  = rem >> 7;      // (kh*3+kw)
    int ci  = rem & 127;
    int kh  = kk / 3;
    int kw  = kk - kh * 3;
    Wt[o] = f2b(w[(((size_t)co * CIN + ci) * 3 + kh) * 3 + kw]);
  }
#pragma unroll
  for (int j = 0; j < 4; ++j) {
    unsigned e = (unsigned)o + j * 294912u;
    if (e < 933888u) {
      unsigned n  = e / 29184u;         // 228*128
      unsigned rm = e - n * 29184u;
      unsigned bp = rm >> 7;            // border pixel 0..227
      unsigned ch = rm & 127u;
      unsigned ih, iw;
      if (bp < 58u)       { ih = 0;  iw = bp; }
      else if (bp < 116u) { ih = 57; iw = bp - 58u; }
      else { unsigned c2 = bp - 116u; ih = 1u + (c2 >> 1); iw = (c2 & 1u) ? 57u : 0u; }
      xt[(((size_t)n * HP + ih) * HP + iw) * CIN + ch] = (u16)0;
    }
  }
}

// ---- GEMM: grid 1568 (784 m-tiles x 2 co-tiles), block 256 (4 waves).
// 128x128 tile, BK=64, 18 K-tiles. SINGLE 32 KB LDS buffer; per K-tile:
// sync (readers done) -> stage 32 KB via global_load_lds -> sync (drain) -> MFMA.
// Inter-block overlap (4 blocks/CU) hides the stage drain (m97/m114 pattern).

__device__ __forceinline__ int uX_off(int kt) {
  int ksp = kt >> 1;
  int kh  = (ksp >= 6) ? 2 : ((ksp >= 3) ? 1 : 0);
  int kw  = ksp - kh * 3;
  return (kh * HP + kw) * CIN + ((kt & 1) << 6);
}

__global__ __launch_bounds__(256, 4) void k_conv_gemm(
    const u16* __restrict__ xt, const u16* __restrict__ Wt,
    const float* __restrict__ bias, float* __restrict__ out) {
  __shared__ u16 lW[8192];   // 128 rows x 64 k, 16B pieces XOR-swizzled
  __shared__ u16 lX[8192];

  const int tid  = threadIdx.x;
  const int wave = tid >> 6;
  const int lane = tid & 63;

  // XCD chunk swizzle (1568 = 8*196 exact, bijective). Decode keeps the two
  // co-tiles of one m-tile (by=0,1) adjacent -> same XCD -> shared X panel in L2.
  const int bid  = blockIdx.x;
  const int orig = (bid & 7) * 196 + (bid >> 3);
  const int bx   = orig >> 1;
  const int by   = orig & 1;
  const int m0   = bx * 128;
  const int co0  = by * 128;

  const int r  = lane & 15;
  const int q  = lane >> 4;
  const int r7 = r & 7;
  const int wm = (wave & 1) * 64;    // m offset of this wave's 64x64
  const int wc = (wave >> 1) * 64;   // co offset

  // staging lane map: 8 rows x 8 swizzled 16B pieces per instruction
  const int rsub = lane >> 3;
  const int pso  = ((lane & 7) ^ rsub) * 8;

  int pbX[4], pbW[4], ldo[4];
#pragma unroll
  for (int c = 0; c < 4; ++c) {
    const int rowb = wave * 32 + c * 8;
    const int m  = m0 + rowb + rsub;
    const int n  = m / HWP;
    const int s  = m - n * HWP;
    const int oh = s / WWD;
    const int ow = s - oh * WWD;
    pbX[c] = ((n * HP + oh) * HP + ow) * CIN + pso;
    pbW[c] = (co0 + rowb + rsub) * KTOT + pso;
    ldo[c] = rowb * 64;
  }
  float bias_r[4];
#pragma unroll
  for (int tj = 0; tj < 4; ++tj) bias_r[tj] = bias[co0 + wc + tj * 16 + r];

  f32x4 acc[4][4];
#pragma unroll
  for (int i = 0; i < 4; ++i)
#pragma unroll
    for (int j = 0; j < 4; ++j) acc[i][j] = (f32x4){0.f, 0.f, 0.f, 0.f};

#pragma unroll 1
  for (int kt = 0; kt < 18; ++kt) {
    const int uxo = uX_off(kt);
    const int uwo = kt * 64;
    __syncthreads();   // all waves done reading LDS from previous K-tile
#pragma unroll
    for (int c = 0; c < 4; ++c) {
      load_lds16(xt + pbX[c] + uxo, &lX[ldo[c]]);   // X first (higher latency)
      load_lds16(Wt + pbW[c] + uwo, &lW[ldo[c]]);
    }
    __syncthreads();   // drains vmcnt -> staged data visible

#pragma unroll
    for (int kk = 0; kk < 2; ++kk) {
      bf16x8 a[4], b[4];
      const int sw = ((kk * 4 + q) ^ r7) * 8;   // swizzled segment offset (elems)
#pragma unroll
      for (int ti = 0; ti < 4; ++ti)
        a[ti] = *(const bf16x8*)&lX[(wm + ti * 16 + r) * 64 + sw];
#pragma unroll
      for (int tj = 0; tj < 4; ++tj)
        b[tj] = *(const bf16x8*)&lW[(wc + tj * 16 + r) * 64 + sw];
#pragma unroll
      for (int ti = 0; ti < 4; ++ti)
#pragma unroll
        for (int tj = 0; tj < 4; ++tj)
          acc[ti][tj] = __builtin_amdgcn_mfma_f32_16x16x32_bf16(
              a[ti], b[tj], acc[ti][tj], 0, 0, 0);
    }
  }

  // Epilogue: mfma(a=X, b=W) -> col(lane&15)=co, row(q*4+e)=m.
  // f32x4 store along s (m4 is 4-aligned, never crosses a 3136-row).
#pragma unroll
  for (int ti = 0; ti < 4; ++ti) {
    const int m4 = m0 + wm + ti * 16 + q * 4;
    const int n  = m4 / HWP;
    const int s  = m4 - n * HWP;
    float* op = out + (size_t)n * COUT * HWP + s;
#pragma unroll
    for (int tj = 0; tj < 4; ++tj) {
      const int co = co0 + wc + tj * 16 + r;
      f32x4 v = acc[ti][tj];
      const float bv = bias_r[tj];
      v[0] += bv; v[1] += bv; v[2] += bv; v[3] += bv;
      *(f32x4*)(op + (size_t)co * HWP) = v;
    }
  }
}

extern "C" void kernel_launch(void* const* d_in, const int* in_sizes, int n_in,
                              void* d_out, int out_size, void* d_ws, size_t ws_size,
                              hipStream_t stream) {
  const float* x    = (const float*)d_in[0];
  const float* w    = (const float*)d_in[1];
  const float* bias = (const float*)d_in[2];
  float* out        = (float*)d_out;

  u16* xt = (u16*)d_ws;                       // 13,778,944 bf16 = 27.6 MB (padded NHWC)
  u16* Wt = xt + (size_t)NB * XTN;            // 294,912 bf16

  k_transform_w<<<dim3(1152), dim3(256), 0, stream>>>(w, Wt, xt);
  k_transpose_x<<<dim3(49, 2, 32), dim3(256), 0, stream>>>(x, xt);
  k_conv_gemm<<<dim3(1568), dim3(256), 0, stream>>>(xt, Wt, bias, out);
}